// Round 1
// baseline (2703.142 us; speedup 1.0000x reference)
//
#include <hip/hip_runtime.h>

// TreeLstmDecoder: B=64 trees, K=4, D=6, V=600, L=256, N_PER=1365, N=87360.
// Sequential schedule of 21 groups; states stored per-level as (tree, pos) so
// parent/sibling "gathers" are identity row reads. All GEMMs are C = A * B^T
// with K=256, bf16 operands, fp32 accumulate.

typedef unsigned short u16;
typedef u16 u16x8 __attribute__((ext_vector_type(8)));

#define KARY 4
#define NPER 1365
#define LDIM 256
#define VDIM 600
#define VD2  602

__device__ __forceinline__ float b2f(u16 h) {
  union { unsigned u; float f; } v; v.u = ((unsigned)h) << 16; return v.f;
}
__device__ __forceinline__ u16 f2bf(float f) {
  union { float f; unsigned u; } v; v.f = f;
  unsigned r = v.u + 0x7fff + ((v.u >> 16) & 1);
  return (u16)(r >> 16);
}
__device__ __forceinline__ float sigm(float x) { return 1.f / (1.f + expf(-x)); }

// ---------------- pack kernels (run every call; ws is re-poisoned) ----------

__global__ void k_cvt(const float* __restrict__ src, u16* __restrict__ dst, int n) {
  int i = blockIdx.x * 256 + threadIdx.x;
  if (i < n) dst[i] = f2bf(src[i]);
}

// W_ih [1024,600] fp32 -> W_ihT [600,1024] bf16 (so the per-node embedding
// gather becomes one contiguous 2KB row read)
__global__ void k_trans_ih(const float* __restrict__ src, u16* __restrict__ dst) {
  int i = blockIdx.x * 256 + threadIdx.x;
  if (i < 1024 * VDIM) {
    int r = i / VDIM; int c = i - r * VDIM;
    dst[c * 1024 + r] = f2bf(src[i]);
  }
}

// Wext [602,256]: rows 0..599 = W_label, 600 = W_depth, 601 = W_width.
__global__ void k_wext(const float* __restrict__ wlab, const float* __restrict__ wd,
                       const float* __restrict__ ww, const float* __restrict__ bl,
                       const float* __restrict__ bd, const float* __restrict__ bw,
                       u16* __restrict__ wext, float* __restrict__ be) {
  int i = blockIdx.x * 256 + threadIdx.x;
  if (i < VD2 * LDIM) {
    int r = i >> 8, c = i & 255;
    float v = (r < VDIM) ? wlab[r * LDIM + c] : ((r == VDIM) ? wd[c] : ww[c]);
    wext[i] = f2bf(v);
  }
  if (i < VD2) be[i] = (i < VDIM) ? bl[i] : ((i == VDIM) ? bd[0] : bw[0]);
}

__global__ void k_bias2(const float* __restrict__ a, const float* __restrict__ b,
                        float* __restrict__ d, int n) {
  int i = blockIdx.x * 256 + threadIdx.x;
  if (i < n) d[i] = a[i] + b[i];
}

// ---------------- generic tiled GEMM: C[m,n] = act(sum_k A[m,k]*B[n,k] + bias)
// A: [M,256] bf16, B: [N,256] bf16 (row-major, K contiguous). M % 64 == 0.
// HAS_A2: add A2*B2^T (K again 256). OUT_BF16: store bf16 else fp32.

template<int HAS_A2, int ACT_TANH, int OUT_BF16>
__global__ __launch_bounds__(256) void k_gemm(
    const u16* __restrict__ A1, const u16* __restrict__ B1,
    const u16* __restrict__ A2, const u16* __restrict__ B2,
    const float* __restrict__ bias, void* __restrict__ Cv, int N, int ldc) {
  __shared__ __align__(16) float As[32][68];
  __shared__ __align__(16) float Bs[32][68];
  const int m0 = blockIdx.x * 64;
  const int n0 = blockIdx.y * 64;
  const int tid = threadIdx.x;
  const int lr = tid >> 2;          // 0..63 tile row
  const int lk = (tid & 3) << 3;    // 0,8,16,24 k-offset
  const int tm = tid >> 4;          // 0..15
  const int tn = tid & 15;          // 0..15

  float acc[4][4];
#pragma unroll
  for (int r = 0; r < 4; ++r)
#pragma unroll
    for (int c = 0; c < 4; ++c) acc[r][c] = 0.f;

  const int NT = HAS_A2 ? 16 : 8;
  for (int tI = 0; tI < NT; ++tI) {
    const int kk0 = (tI & 7) * 32;
    const u16* Au = (HAS_A2 && tI >= 8) ? A2 : A1;
    const u16* Bu = (HAS_A2 && tI >= 8) ? B2 : B1;

    u16x8 av = *(const u16x8*)(Au + (m0 + lr) * 256 + kk0 + lk);
    u16x8 bv = {0, 0, 0, 0, 0, 0, 0, 0};
    int nrow = n0 + lr;
    if (nrow < N) bv = *(const u16x8*)(Bu + nrow * 256 + kk0 + lk);

    __syncthreads();
#pragma unroll
    for (int jj = 0; jj < 8; ++jj) {
      As[lk + jj][lr] = b2f(av[jj]);
      Bs[lk + jj][lr] = b2f(bv[jj]);
    }
    __syncthreads();

#pragma unroll
    for (int kk = 0; kk < 32; ++kk) {
      float4 a = *(const float4*)&As[kk][tm * 4];
      float4 b = *(const float4*)&Bs[kk][tn * 4];
      acc[0][0] += a.x * b.x; acc[0][1] += a.x * b.y; acc[0][2] += a.x * b.z; acc[0][3] += a.x * b.w;
      acc[1][0] += a.y * b.x; acc[1][1] += a.y * b.y; acc[1][2] += a.y * b.z; acc[1][3] += a.y * b.w;
      acc[2][0] += a.z * b.x; acc[2][1] += a.z * b.y; acc[2][2] += a.z * b.z; acc[2][3] += a.z * b.w;
      acc[3][0] += a.w * b.x; acc[3][1] += a.w * b.y; acc[3][2] += a.w * b.z; acc[3][3] += a.w * b.w;
    }
  }

#pragma unroll
  for (int r = 0; r < 4; ++r) {
    int row = m0 + tm * 4 + r;
#pragma unroll
    for (int c = 0; c < 4; ++c) {
      int col = n0 + tn * 4 + c;
      if (col < N) {
        float v = acc[r][c];
        if (bias) v += bias[col];
        if (ACT_TANH) v = tanhf(v);
        if (OUT_BF16) ((u16*)Cv)[row * ldc + col] = f2bf(v);
        else          ((float*)Cv)[row * ldc + col] = v;
      }
    }
  }
}

// ---------------- row-wise log_softmax over 600 + 2 sigmoid heads -----------
// one block (256 thr) per node; logits [G,602] fp32 -> out[idx,602]

__global__ __launch_bounds__(256) void k_softmax(
    const float* __restrict__ logits, float* __restrict__ out,
    int pcs, int start_d, int s) {
  __shared__ float sred[8];
  __shared__ float sbc;
  int g = blockIdx.x, u = threadIdx.x;
  int t = g >> pcs, j = g - (t << pcs);
  int idx = t * NPER + start_d + j * KARY + s;
  const float* row = logits + (size_t)g * VD2;
  float* orow = out + (size_t)idx * VD2;

  float x0 = row[u];
  float x1 = row[256 + u];
  float x2 = (u < 88) ? row[512 + u] : -1e30f;
  float m = fmaxf(fmaxf(x0, x1), x2);
#pragma unroll
  for (int o = 32; o > 0; o >>= 1) m = fmaxf(m, __shfl_down(m, o, 64));
  if ((u & 63) == 0) sred[u >> 6] = m;
  __syncthreads();
  if (u == 0) sbc = fmaxf(fmaxf(sred[0], sred[1]), fmaxf(sred[2], sred[3]));
  __syncthreads();
  m = sbc;
  float e = expf(x0 - m) + expf(x1 - m) + ((u < 88) ? expf(x2 - m) : 0.f);
#pragma unroll
  for (int o = 32; o > 0; o >>= 1) e += __shfl_down(e, o, 64);
  if ((u & 63) == 0) sred[4 + (u >> 6)] = e;
  __syncthreads();
  if (u == 0) sbc = m + logf(sred[4] + sred[5] + sred[6] + sred[7]);
  __syncthreads();
  float logZ = sbc;
  orow[u] = x0 - logZ;
  orow[256 + u] = x1 - logZ;
  if (u < 88) orow[512 + u] = x2 - logZ;
  if (u == 0) orow[600] = sigm(row[600]);
  if (u == 1) orow[601] = sigm(row[601]);
}

// ---------------- LSTM elementwise: gates = gemm + W_ihT[lab] + bias --------
// one block per node, thread = hidden unit. strided: out row = t*LS + j*K + s
// (per-level parent buffer); else out row = g (sibling group buffer).

__global__ __launch_bounds__(256) void k_lstm(
    const u16* __restrict__ gate_gemm, const u16* __restrict__ wihT,
    const float* __restrict__ bias, const u16* __restrict__ c_in,
    const int* __restrict__ feat, u16* __restrict__ h_out, u16* __restrict__ c_out,
    int pcs, int LS, int start_d, int s, int strided) {
  int g = blockIdx.x, u = threadIdx.x;
  int t = g >> pcs, j = g - (t << pcs);
  int p = j * KARY + s;
  int idx = t * NPER + start_d + p;
  int lab = feat[idx];
  const u16* wr = wihT + lab * 1024;
  float gi = b2f(wr[u])       + bias[u];
  float gf = b2f(wr[256 + u]) + bias[256 + u];
  float gg = b2f(wr[512 + u]) + bias[512 + u];
  float go = b2f(wr[768 + u]) + bias[768 + u];
  if (gate_gemm) {
    const u16* gr = gate_gemm + g * 1024;
    gi += b2f(gr[u]); gf += b2f(gr[256 + u]);
    gg += b2f(gr[512 + u]); go += b2f(gr[768 + u]);
  }
  float c = c_in ? b2f(c_in[g * 256 + u]) : 0.f;
  float cn = sigm(gf) * c + sigm(gi) * tanhf(gg);
  float hn = sigm(go) * tanhf(cn);
  int orow = strided ? (t * LS + p) : g;
  h_out[orow * 256 + u] = f2bf(hn);
  c_out[orow * 256 + u] = f2bf(cn);
}

// ---------------- host ------------------------------------------------------

#define LGEMM(HA2, ACT, OBF, A1, B1, A2, B2, BIAS, C, M, N)                    \
  k_gemm<HA2, ACT, OBF><<<dim3((M) / 64, ((N) + 63) / 64), 256, 0, stream>>>(  \
      (const u16*)(A1), (const u16*)(B1), (const u16*)(A2), (const u16*)(B2),  \
      (BIAS), (void*)(C), (N), (N))

extern "C" void kernel_launch(void* const* d_in, const int* in_sizes, int n_in,
                              void* d_out, int out_size, void* d_ws, size_t ws_size,
                              hipStream_t stream) {
  const float* z    = (const float*)d_in[0];
  const int*   feat = (const int*)d_in[1];
  const float* Wihp = (const float*)d_in[2];
  const float* Whhp = (const float*)d_in[3];
  const float* bihp = (const float*)d_in[4];
  const float* bhhp = (const float*)d_in[5];
  const float* Wihs = (const float*)d_in[6];
  const float* Whhs = (const float*)d_in[7];
  const float* bihs = (const float*)d_in[8];
  const float* bhhs = (const float*)d_in[9];
  const float* Upar = (const float*)d_in[10];
  const float* Usib = (const float*)d_in[11];
  const float* Wlab = (const float*)d_in[12];
  const float* blab = (const float*)d_in[13];
  const float* Wd   = (const float*)d_in[14];
  const float* bd   = (const float*)d_in[15];
  const float* Ww   = (const float*)d_in[16];
  const float* bw   = (const float*)d_in[17];
  float* out = (float*)d_out;

  char* w = (char*)d_ws;
  auto alloc = [&](size_t bytes) {
    char* p = w; w += (bytes + 255) & ~(size_t)255; return p;
  };
  u16*   UP    = (u16*)alloc(65536 * 2);
  u16*   US    = (u16*)alloc(65536 * 2);
  u16*   WEXT  = (u16*)alloc(VD2 * 256 * 2);
  float* BE    = (float*)alloc(VD2 * 4);
  u16*   WHHP  = (u16*)alloc(1024 * 256 * 2);
  u16*   WHHS  = (u16*)alloc(1024 * 256 * 2);
  u16*   WIHPT = (u16*)alloc(VDIM * 1024 * 2);
  u16*   WIHST = (u16*)alloc(VDIM * 1024 * 2);
  float* BP    = (float*)alloc(1024 * 4);
  float* BS    = (float*)alloc(1024 * 4);
  u16*   ZBF   = (u16*)alloc(64 * 256 * 2);
  const size_t SB = (size_t)16384 * 256 * 2;
  u16* HP[2] = {(u16*)alloc(SB), (u16*)alloc(SB)};
  u16* CP[2] = {(u16*)alloc(SB), (u16*)alloc(SB)};
  u16* HS[2] = {(u16*)alloc(SB), (u16*)alloc(SB)};
  u16* CS[2] = {(u16*)alloc(SB), (u16*)alloc(SB)};
  u16*   HPRED  = (u16*)alloc(SB);
  float* LOGITS = (float*)alloc((size_t)16384 * VD2 * 4);
  u16*   GATES  = (u16*)alloc((size_t)16384 * 1024 * 2);

  // ---- pack weights (bf16) every call (ws is re-poisoned between calls)
  k_cvt<<<(65536 + 255) / 256, 256, 0, stream>>>(Upar, UP, 65536);
  k_cvt<<<(65536 + 255) / 256, 256, 0, stream>>>(Usib, US, 65536);
  k_cvt<<<(262144 + 255) / 256, 256, 0, stream>>>(Whhp, WHHP, 262144);
  k_cvt<<<(262144 + 255) / 256, 256, 0, stream>>>(Whhs, WHHS, 262144);
  k_cvt<<<(16384 + 255) / 256, 256, 0, stream>>>(z, ZBF, 16384);
  k_trans_ih<<<(1024 * VDIM + 255) / 256, 256, 0, stream>>>(Wihp, WIHPT);
  k_trans_ih<<<(1024 * VDIM + 255) / 256, 256, 0, stream>>>(Wihs, WIHST);
  k_wext<<<(VD2 * 256 + 255) / 256, 256, 0, stream>>>(Wlab, Wd, Ww, blab, bd, bw, WEXT, BE);
  k_bias2<<<4, 256, 0, stream>>>(bihp, bhhp, BP, 1024);
  k_bias2<<<4, 256, 0, stream>>>(bihs, bhhs, BS, 1024);

  const int starts[6] = {0, 1, 5, 21, 85, 341};

  // ---- d = 0 (roots): h_par = z, c_par = 0, no sibling
  LGEMM(0, 1, 1, ZBF, UP, nullptr, nullptr, nullptr, HPRED, 64, 256);
  LGEMM(0, 0, 0, HPRED, WEXT, nullptr, nullptr, BE, LOGITS, 64, VD2);
  k_softmax<<<64, 256, 0, stream>>>(LOGITS, out, 0, 0, 0);
  LGEMM(0, 0, 1, ZBF, WHHP, nullptr, nullptr, nullptr, GATES, 64, 1024);
  k_lstm<<<64, 256, 0, stream>>>(GATES, WIHPT, BP, nullptr, feat,
                                 HP[0], CP[0], 0, 1, 0, 0, 1);
  int hp_prev = 0;

  // ---- d = 1 .. 5
  for (int d = 1; d < 6; ++d) {
    const int G = 64 << (2 * (d - 1));
    const int pcs = 2 * (d - 1);
    const int LS = 1 << (2 * d);
    int sib_prev = -1;
    for (int s = 0; s < KARY; ++s) {
      u16* HPAR = HP[hp_prev];
      u16* CPAR = CP[hp_prev];
      // h_pred = tanh(h_par Up^T [+ h_prev Us^T])
      if (s == 0)
        LGEMM(0, 1, 1, HPAR, UP, nullptr, nullptr, nullptr, HPRED, G, 256);
      else
        LGEMM(1, 1, 1, HPAR, UP, HS[sib_prev], US, nullptr, HPRED, G, 256);
      // logits (+ depth/width heads as rows 600/601)
      LGEMM(0, 0, 0, HPRED, WEXT, nullptr, nullptr, BE, LOGITS, G, VD2);
      k_softmax<<<G, 256, 0, stream>>>(LOGITS, out, pcs, starts[d], s);
      // parent LSTM (skipped at leaves: h_p of depth 5 is never read)
      if (d < 5) {
        LGEMM(0, 0, 1, HPAR, WHHP, nullptr, nullptr, nullptr, GATES, G, 1024);
        k_lstm<<<G, 256, 0, stream>>>(GATES, WIHPT, BP, CPAR, feat,
                                      HP[1 - hp_prev], CP[1 - hp_prev],
                                      pcs, LS, starts[d], s, 1);
      }
      // sibling LSTM (skipped for last sibling: its h_s is never read)
      if (s < KARY - 1) {
        int dst = (sib_prev < 0) ? 0 : 1 - sib_prev;
        if (s == 0) {
          k_lstm<<<G, 256, 0, stream>>>(nullptr, WIHST, BS, nullptr, feat,
                                        HS[dst], CS[dst], pcs, LS, starts[d], s, 0);
        } else {
          LGEMM(0, 0, 1, HS[sib_prev], WHHS, nullptr, nullptr, nullptr, GATES, G, 1024);
          k_lstm<<<G, 256, 0, stream>>>(GATES, WIHST, BS, CS[sib_prev], feat,
                                        HS[dst], CS[dst], pcs, LS, starts[d], s, 0);
        }
        sib_prev = dst;
      }
    }
    if (d < 5) hp_prev = 1 - hp_prev;
  }
  (void)in_sizes; (void)n_in; (void)out_size; (void)ws_size;
}

// Round 2
// 1745.062 us; speedup vs baseline: 1.5490x; 1.5490x over previous
//
#include <hip/hip_runtime.h>

// TreeLstmDecoder: B=64 trees, K=4, D=6, V=600, L=256, N_PER=1365, N=87360.
// States stored per-level as (tree,pos) so parent/sibling gathers are identity.
// All GEMMs: C = A * B^T, K=256, bf16 operands, fp32 accumulate via MFMA.
// Hoisted per-depth: PPART = Hpar@Up^T and GATESP = Hpar@Whhp^T (shared by all
// 4 sibling groups at a depth).

typedef unsigned short u16;
typedef short bf16x8 __attribute__((ext_vector_type(8)));
typedef float f32x4 __attribute__((ext_vector_type(4)));

#define KARY 4
#define NPER 1365
#define LDIM 256
#define VDIM 600
#define VD2  602

__device__ __forceinline__ float b2f(u16 h) {
  union { unsigned u; float f; } v; v.u = ((unsigned)h) << 16; return v.f;
}
__device__ __forceinline__ u16 f2bf(float f) {
  union { float f; unsigned u; } v; v.f = f;
  unsigned r = v.u + 0x7fff + ((v.u >> 16) & 1);
  return (u16)(r >> 16);
}
__device__ __forceinline__ float sigm(float x) { return 1.f / (1.f + expf(-x)); }

// ---------------- pack kernels (run every call; ws is re-poisoned) ----------

__global__ void k_cvt(const float* __restrict__ src, u16* __restrict__ dst, int n) {
  int i = blockIdx.x * 256 + threadIdx.x;
  if (i < n) dst[i] = f2bf(src[i]);
}

// W_ih [1024,600] fp32 -> W_ihT [600,1024] bf16
__global__ void k_trans_ih(const float* __restrict__ src, u16* __restrict__ dst) {
  int i = blockIdx.x * 256 + threadIdx.x;
  if (i < 1024 * VDIM) {
    int r = i / VDIM; int c = i - r * VDIM;
    dst[c * 1024 + r] = f2bf(src[i]);
  }
}

// Wext [602,256]: rows 0..599 = W_label, 600 = W_depth, 601 = W_width.
__global__ void k_wext(const float* __restrict__ wlab, const float* __restrict__ wd,
                       const float* __restrict__ ww, const float* __restrict__ bl,
                       const float* __restrict__ bd, const float* __restrict__ bw,
                       u16* __restrict__ wext, float* __restrict__ be) {
  int i = blockIdx.x * 256 + threadIdx.x;
  if (i < VD2 * LDIM) {
    int r = i >> 8, c = i & 255;
    float v = (r < VDIM) ? wlab[r * LDIM + c] : ((r == VDIM) ? wd[c] : ww[c]);
    wext[i] = f2bf(v);
  }
  if (i < VD2) be[i] = (i < VDIM) ? bl[i] : ((i == VDIM) ? bd[0] : bw[0]);
}

__global__ void k_bias2(const float* __restrict__ a, const float* __restrict__ b,
                        float* __restrict__ d, int n) {
  int i = blockIdx.x * 256 + threadIdx.x;
  if (i < n) d[i] = a[i] + b[i];
}

__global__ void k_tanh(const u16* __restrict__ src, u16* __restrict__ dst, int n) {
  int i = blockIdx.x * 256 + threadIdx.x;
  if (i < n) dst[i] = f2bf(tanhf(b2f(src[i])));
}

// ---------------- MFMA GEMM: C[m,n] = act(sum_k A[m,k]*B[n,k] + bias + Cadd)
// A:[M,256] bf16, B:[N,256] bf16 (row-major, K contiguous). BM=BN=128, BK=32,
// 4 waves each computing 64x64 (4x4 tiles of 16x16x32 mfma).
// No load guards needed: OOB rows/cols produce garbage in rows/cols that are
// never stored (each C element's dot product touches only its own A/B row).

template<int ACT_TANH, int OUT_BF16>
__global__ __launch_bounds__(256) void k_mm(
    const u16* __restrict__ A, const u16* __restrict__ B,
    const float* __restrict__ bias, const u16* __restrict__ Cadd,
    void* __restrict__ Cv, int M, int N) {
  __shared__ __align__(16) u16 As[128 * 40];  // stride 40 elems (80B): 2-way-free banks
  __shared__ __align__(16) u16 Bs[128 * 40];
  const int m0 = blockIdx.x * 128, n0 = blockIdx.y * 128;
  const int tid = threadIdx.x;
  const int wave = tid >> 6, lane = tid & 63;
  const int quad = lane >> 4, lr = lane & 15;
  const int wm = (wave >> 1) * 64, wn = (wave & 1) * 64;
  const int srow = tid >> 2;            // 0..63 staging row (2 rounds)
  const int sch = (tid & 3) << 3;       // k-chunk elem offset 0,8,16,24

  f32x4 acc[4][4] = {};

  for (int t = 0; t < 8; ++t) {
    const int kk = t * 32;
    bf16x8 a0 = *(const bf16x8*)(A + (size_t)(m0 + srow) * 256 + kk + sch);
    bf16x8 a1 = *(const bf16x8*)(A + (size_t)(m0 + srow + 64) * 256 + kk + sch);
    bf16x8 b0 = *(const bf16x8*)(B + (size_t)(n0 + srow) * 256 + kk + sch);
    bf16x8 b1 = *(const bf16x8*)(B + (size_t)(n0 + srow + 64) * 256 + kk + sch);
    __syncthreads();
    *(bf16x8*)&As[srow * 40 + sch] = a0;
    *(bf16x8*)&As[(srow + 64) * 40 + sch] = a1;
    *(bf16x8*)&Bs[srow * 40 + sch] = b0;
    *(bf16x8*)&Bs[(srow + 64) * 40 + sch] = b1;
    __syncthreads();

    bf16x8 af[4], bfr[4];
#pragma unroll
    for (int tm = 0; tm < 4; ++tm)
      af[tm] = *(const bf16x8*)&As[(wm + tm * 16 + lr) * 40 + quad * 8];
#pragma unroll
    for (int tn = 0; tn < 4; ++tn)
      bfr[tn] = *(const bf16x8*)&Bs[(wn + tn * 16 + lr) * 40 + quad * 8];
#pragma unroll
    for (int tm = 0; tm < 4; ++tm)
#pragma unroll
      for (int tn = 0; tn < 4; ++tn)
        acc[tm][tn] = __builtin_amdgcn_mfma_f32_16x16x32_bf16(
            af[tm], bfr[tn], acc[tm][tn], 0, 0, 0);
  }

  // epilogue: C/D layout col=lane&15, row=quad*4+reg
#pragma unroll
  for (int tn = 0; tn < 4; ++tn) {
    int col = n0 + wn + tn * 16 + lr;
    if (col >= N) continue;
    float bv = bias ? bias[col] : 0.f;
#pragma unroll
    for (int tm = 0; tm < 4; ++tm) {
#pragma unroll
      for (int r = 0; r < 4; ++r) {
        int row = m0 + wm + tm * 16 + quad * 4 + r;
        if (row >= M) continue;
        float v = acc[tm][tn][r] + bv;
        if (Cadd) v += b2f(Cadd[(size_t)row * N + col]);
        if (ACT_TANH) v = tanhf(v);
        if (OUT_BF16) ((u16*)Cv)[(size_t)row * N + col] = f2bf(v);
        else          ((float*)Cv)[(size_t)row * N + col] = v;
      }
    }
  }
}

// ---------------- row-wise log_softmax over 600 + 2 sigmoid heads -----------

__global__ __launch_bounds__(256) void k_softmax(
    const float* __restrict__ logits, float* __restrict__ out,
    int pcs, int start_d, int s) {
  __shared__ float sred[8];
  __shared__ float sbc;
  int g = blockIdx.x, u = threadIdx.x;
  int t = g >> pcs, j = g - (t << pcs);
  int idx = t * NPER + start_d + j * KARY + s;
  const float* row = logits + (size_t)g * VD2;
  float* orow = out + (size_t)idx * VD2;

  float x0 = row[u];
  float x1 = row[256 + u];
  float x2 = (u < 88) ? row[512 + u] : -1e30f;
  float m = fmaxf(fmaxf(x0, x1), x2);
#pragma unroll
  for (int o = 32; o > 0; o >>= 1) m = fmaxf(m, __shfl_down(m, o, 64));
  if ((u & 63) == 0) sred[u >> 6] = m;
  __syncthreads();
  if (u == 0) sbc = fmaxf(fmaxf(sred[0], sred[1]), fmaxf(sred[2], sred[3]));
  __syncthreads();
  m = sbc;
  float e = expf(x0 - m) + expf(x1 - m) + ((u < 88) ? expf(x2 - m) : 0.f);
#pragma unroll
  for (int o = 32; o > 0; o >>= 1) e += __shfl_down(e, o, 64);
  if ((u & 63) == 0) sred[4 + (u >> 6)] = e;
  __syncthreads();
  if (u == 0) sbc = m + logf(sred[4] + sred[5] + sred[6] + sred[7]);
  __syncthreads();
  float logZ = sbc;
  orow[u] = x0 - logZ;
  orow[256 + u] = x1 - logZ;
  if (u < 88) orow[512 + u] = x2 - logZ;
  if (u == 0) orow[600] = sigm(row[600]);
  if (u == 1) orow[601] = sigm(row[601]);
}

// ---------------- LSTM elementwise ------------------------------------------

__global__ __launch_bounds__(256) void k_lstm(
    const u16* __restrict__ gate_gemm, const u16* __restrict__ wihT,
    const float* __restrict__ bias, const u16* __restrict__ c_in,
    const int* __restrict__ feat, u16* __restrict__ h_out, u16* __restrict__ c_out,
    int pcs, int LS, int start_d, int s, int strided) {
  int g = blockIdx.x, u = threadIdx.x;
  int t = g >> pcs, j = g - (t << pcs);
  int p = j * KARY + s;
  int idx = t * NPER + start_d + p;
  int lab = feat[idx];
  const u16* wr = wihT + lab * 1024;
  float gi = b2f(wr[u])       + bias[u];
  float gf = b2f(wr[256 + u]) + bias[256 + u];
  float gg = b2f(wr[512 + u]) + bias[512 + u];
  float go = b2f(wr[768 + u]) + bias[768 + u];
  if (gate_gemm) {
    const u16* gr = gate_gemm + (size_t)g * 1024;
    gi += b2f(gr[u]); gf += b2f(gr[256 + u]);
    gg += b2f(gr[512 + u]); go += b2f(gr[768 + u]);
  }
  float c = c_in ? b2f(c_in[(size_t)g * 256 + u]) : 0.f;
  float cn = sigm(gf) * c + sigm(gi) * tanhf(gg);
  float hn = sigm(go) * tanhf(cn);
  int orow = strided ? (t * LS + p) : g;
  h_out[(size_t)orow * 256 + u] = f2bf(hn);
  c_out[(size_t)orow * 256 + u] = f2bf(cn);
}

// ---------------- host ------------------------------------------------------

#define LMM(ACT, OBF, A, Bm, BIAS, CADD, C, M, N)                              \
  k_mm<ACT, OBF><<<dim3(((M) + 127) / 128, ((N) + 127) / 128), 256, 0,         \
                   stream>>>((const u16*)(A), (const u16*)(Bm), (BIAS),        \
                             (const u16*)(CADD), (void*)(C), (M), (N))

extern "C" void kernel_launch(void* const* d_in, const int* in_sizes, int n_in,
                              void* d_out, int out_size, void* d_ws, size_t ws_size,
                              hipStream_t stream) {
  const float* z    = (const float*)d_in[0];
  const int*   feat = (const int*)d_in[1];
  const float* Wihp = (const float*)d_in[2];
  const float* Whhp = (const float*)d_in[3];
  const float* bihp = (const float*)d_in[4];
  const float* bhhp = (const float*)d_in[5];
  const float* Wihs = (const float*)d_in[6];
  const float* Whhs = (const float*)d_in[7];
  const float* bihs = (const float*)d_in[8];
  const float* bhhs = (const float*)d_in[9];
  const float* Upar = (const float*)d_in[10];
  const float* Usib = (const float*)d_in[11];
  const float* Wlab = (const float*)d_in[12];
  const float* blab = (const float*)d_in[13];
  const float* Wd   = (const float*)d_in[14];
  const float* bd   = (const float*)d_in[15];
  const float* Ww   = (const float*)d_in[16];
  const float* bw   = (const float*)d_in[17];
  float* out = (float*)d_out;

  char* w = (char*)d_ws;
  auto alloc = [&](size_t bytes) {
    char* p = w; w += (bytes + 255) & ~(size_t)255; return p;
  };
  u16*   UP    = (u16*)alloc(65536 * 2);
  u16*   US    = (u16*)alloc(65536 * 2);
  u16*   WEXT  = (u16*)alloc(VD2 * 256 * 2);
  float* BE    = (float*)alloc(VD2 * 4);
  u16*   WHHP  = (u16*)alloc(1024 * 256 * 2);
  u16*   WHHS  = (u16*)alloc(1024 * 256 * 2);
  u16*   WIHPT = (u16*)alloc(VDIM * 1024 * 2);
  u16*   WIHST = (u16*)alloc(VDIM * 1024 * 2);
  float* BP    = (float*)alloc(1024 * 4);
  float* BS    = (float*)alloc(1024 * 4);
  u16*   ZBF   = (u16*)alloc(64 * 256 * 2);
  const size_t SB = (size_t)16384 * 256 * 2;
  u16* HP[2] = {(u16*)alloc(SB), (u16*)alloc(SB)};
  u16* CP[2] = {(u16*)alloc(SB), (u16*)alloc(SB)};
  u16* HS[2] = {(u16*)alloc(SB), (u16*)alloc(SB)};
  u16* CS[2] = {(u16*)alloc(SB), (u16*)alloc(SB)};
  u16*   HPRED  = (u16*)alloc(SB);
  u16*   PP     = (u16*)alloc(SB);                       // hoisted Hpar@Up^T
  float* LOGITS = (float*)alloc((size_t)16384 * VD2 * 4);
  u16*   GATES  = (u16*)alloc((size_t)16384 * 1024 * 2); // sibling gates
  u16*   GATESP = (u16*)alloc((size_t)4096 * 1024 * 2);  // hoisted parent gates

  // ---- pack weights (bf16) every call
  k_cvt<<<(65536 + 255) / 256, 256, 0, stream>>>(Upar, UP, 65536);
  k_cvt<<<(65536 + 255) / 256, 256, 0, stream>>>(Usib, US, 65536);
  k_cvt<<<(262144 + 255) / 256, 256, 0, stream>>>(Whhp, WHHP, 262144);
  k_cvt<<<(262144 + 255) / 256, 256, 0, stream>>>(Whhs, WHHS, 262144);
  k_cvt<<<(16384 + 255) / 256, 256, 0, stream>>>(z, ZBF, 16384);
  k_trans_ih<<<(1024 * VDIM + 255) / 256, 256, 0, stream>>>(Wihp, WIHPT);
  k_trans_ih<<<(1024 * VDIM + 255) / 256, 256, 0, stream>>>(Wihs, WIHST);
  k_wext<<<(VD2 * 256 + 255) / 256, 256, 0, stream>>>(Wlab, Wd, Ww, blab, bd, bw, WEXT, BE);
  k_bias2<<<4, 256, 0, stream>>>(bihp, bhhp, BP, 1024);
  k_bias2<<<4, 256, 0, stream>>>(bihs, bhhs, BS, 1024);

  const int starts[6] = {0, 1, 5, 21, 85, 341};

  // ---- d = 0 (roots): h_par = z, c_par = 0, no sibling
  LMM(1, 1, ZBF, UP, nullptr, nullptr, HPRED, 64, 256);
  LMM(0, 0, HPRED, WEXT, BE, nullptr, LOGITS, 64, VD2);
  k_softmax<<<64, 256, 0, stream>>>(LOGITS, out, 0, 0, 0);
  LMM(0, 1, ZBF, WHHP, nullptr, nullptr, GATES, 64, 1024);
  k_lstm<<<64, 256, 0, stream>>>(GATES, WIHPT, BP, nullptr, feat,
                                 HP[0], CP[0], 0, 1, 0, 0, 1);
  int hp_prev = 0;

  // ---- d = 1 .. 5
  for (int d = 1; d < 6; ++d) {
    const int G = 64 << (2 * (d - 1));
    const int pcs = 2 * (d - 1);
    const int LS = 1 << (2 * d);
    u16* HPAR = HP[hp_prev];
    u16* CPAR = CP[hp_prev];
    // hoisted per-depth GEMMs (identical for all 4 sibling groups)
    LMM(0, 1, HPAR, UP, nullptr, nullptr, PP, G, 256);
    if (d < 5) LMM(0, 1, HPAR, WHHP, nullptr, nullptr, GATESP, G, 1024);
    int sib_prev = -1;
    for (int s = 0; s < KARY; ++s) {
      // h_pred = tanh(PP [+ h_prev Us^T])
      if (s == 0)
        k_tanh<<<(G * 256 + 255) / 256, 256, 0, stream>>>(PP, HPRED, G * 256);
      else
        LMM(1, 1, HS[sib_prev], US, nullptr, PP, HPRED, G, 256);
      // logits (+ depth/width heads as rows 600/601)
      LMM(0, 0, HPRED, WEXT, BE, nullptr, LOGITS, G, VD2);
      k_softmax<<<G, 256, 0, stream>>>(LOGITS, out, pcs, starts[d], s);
      // parent LSTM (gates GEMM hoisted; skipped at leaves)
      if (d < 5) {
        k_lstm<<<G, 256, 0, stream>>>(GATESP, WIHPT, BP, CPAR, feat,
                                      HP[1 - hp_prev], CP[1 - hp_prev],
                                      pcs, LS, starts[d], s, 1);
      }
      // sibling LSTM (skipped for last sibling: its h_s is never read)
      if (s < KARY - 1) {
        int dst = (sib_prev < 0) ? 0 : 1 - sib_prev;
        if (s == 0) {
          k_lstm<<<G, 256, 0, stream>>>(nullptr, WIHST, BS, nullptr, feat,
                                        HS[dst], CS[dst], pcs, LS, starts[d], s, 0);
        } else {
          LMM(0, 1, HS[sib_prev], WHHS, nullptr, nullptr, GATES, G, 1024);
          k_lstm<<<G, 256, 0, stream>>>(GATES, WIHST, BS, CS[sib_prev], feat,
                                        HS[dst], CS[dst], pcs, LS, starts[d], s, 0);
        }
        sib_prev = dst;
      }
    }
    if (d < 5) hp_prev = 1 - hp_prev;
  }
  (void)in_sizes; (void)n_in; (void)out_size; (void)ws_size;
}